// Round 12
// baseline (191.984 us; speedup 1.0000x reference)
//
#include <hip/hip_runtime.h>
#include <hip/hip_bf16.h>

// B=4, S=2048, TEXT_DIM=768, VISION_DIM=768, HIDDEN=512, HEADS=8, HEAD_DIM=64
#define BATCH 4
#define SEQ 2048
#define TDIM 768
#define VDIM 768
#define HID 512
#define NHEADS 8
#define HDIM 64
#define MROWS (BATCH * SEQ)   // 8192
#define NQKV (3 * HID)        // 1536

typedef unsigned short ushort_t;
typedef __attribute__((ext_vector_type(8))) short short8;
typedef __attribute__((ext_vector_type(4))) short short4v;
typedef __attribute__((ext_vector_type(4))) float floatx4;
typedef __attribute__((ext_vector_type(16))) float floatx16;

// 0.125 * log2(e): folded into Q so softmax uses exp2
#define QSCALE 0.18033688011112042f

__device__ __forceinline__ ushort_t bf16_rne(float f) {
    unsigned int u = __float_as_uint(f);
    u = (u + 0x7fffu + ((u >> 16) & 1u)) >> 16;
    return (ushort_t)u;
}

__device__ __forceinline__ void async16(const ushort_t* g, ushort_t* l) {
    __builtin_amdgcn_global_load_lds(
        (const __attribute__((address_space(1))) unsigned int*)g,
        (__attribute__((address_space(3))) unsigned int*)l, 16, 0, 0);
}

// ---------------------------------------------------------------------------
// Pre-pass A: X fp32 -> bf16 (8192x768)
// ---------------------------------------------------------------------------
__global__ __launch_bounds__(256) void conv_x(const float* __restrict__ X,
                                              ushort_t* __restrict__ Xb)
{
    const int i = (blockIdx.x * 256 + threadIdx.x) * 4;
    const floatx4 v = *(const floatx4*)(X + i);
    short4v o;
#pragma unroll
    for (int j = 0; j < 4; ++j) o[j] = (short)bf16_rne(v[j]);
    *(short4v*)(Xb + i) = o;
}

// ---------------------------------------------------------------------------
// Pre-pass B: weight transposes -> bf16 [N][K].
// ---------------------------------------------------------------------------
__global__ __launch_bounds__(256) void transp_w(
    const float* __restrict__ Wq, const float* __restrict__ Wk,
    const float* __restrict__ Wv, const float* __restrict__ Wo,
    ushort_t* __restrict__ Wqkvt, ushort_t* __restrict__ Wot)
{
    __shared__ float tile[32][33];
    const int z = blockIdx.z;
    const float* src;
    ushort_t* dst;
    int R, C;
    if (z < 3) {
        src = (z == 0) ? Wq : (z == 1) ? Wk : Wv;
        dst = Wqkvt + (size_t)z * HID * TDIM;
        R = TDIM; C = HID;
    } else {
        src = Wo; dst = Wot; R = HID; C = VDIM;
    }
    const int tx = threadIdx.x & 31, ty = threadIdx.x >> 5;  // 32 x 8
    const int c0 = blockIdx.x * 32, r0 = blockIdx.y * 32;
    if (c0 >= C || r0 >= R) return;
#pragma unroll
    for (int i = 0; i < 4; ++i)
        tile[ty + i * 8][tx] = src[(size_t)(r0 + ty + i * 8) * C + c0 + tx];
    __syncthreads();
#pragma unroll
    for (int i = 0; i < 4; ++i)
        dst[(size_t)(c0 + ty + i * 8) * R + r0 + tx] = bf16_rne(tile[tx][ty + i * 8]);
}

// ---------------------------------------------------------------------------
// m97-style bf16 MFMA GEMM mainloop: C(128x128) = A[M][K] x Bt[N][K]^T.
// XOR-swizzled LDS (round-9, verified: bank conflicts -> 0, -11.5 us total).
// ---------------------------------------------------------------------------
template<int KD, bool SWAPPED>
__device__ __forceinline__ void gemm128(
    const ushort_t* __restrict__ A, const ushort_t* __restrict__ Bt,
    int m0, int n0, ushort_t* As, ushort_t* Bs, floatx4 (&acc)[4][4])
{
    const int tid  = threadIdx.x;
    const int lane = tid & 63;
    const int w    = tid >> 6;
    const int l15  = lane & 15;
    const int quad = lane >> 4;
    const int wrow = w >> 1;
    const int wcol = w & 1;

    const int srow = lane >> 3;                  // 0..7 = row&7
    const int scol = ((lane & 7) ^ srow) * 8;    // swizzled k elem offset

    const ushort_t* ga = A  + (size_t)(m0 + w * 32 + srow) * KD + scol;
    const ushort_t* gb = Bt + (size_t)(n0 + w * 32 + srow) * KD + scol;
    ushort_t* la = As + (w * 32) * 64;
    ushort_t* lb = Bs + (w * 32) * 64;

    for (int kt = 0; kt < KD; kt += 64) {
#pragma unroll
        for (int i = 0; i < 4; ++i) {
            async16(ga + (size_t)(i * 8) * KD + kt, la + i * 8 * 64);
            async16(gb + (size_t)(i * 8) * KD + kt, lb + i * 8 * 64);
        }
        __syncthreads();
#pragma unroll
        for (int half = 0; half < 2; ++half) {
            const int kk = ((half * 4 + quad) ^ (l15 & 7)) * 8;
            short8 af[4], bf[4];
#pragma unroll
            for (int t = 0; t < 4; ++t) {
                af[t] = *(const short8*)&As[(wrow * 64 + t * 16 + l15) * 64 + kk];
                bf[t] = *(const short8*)&Bs[(wcol * 64 + t * 16 + l15) * 64 + kk];
            }
#pragma unroll
            for (int mi = 0; mi < 4; ++mi)
#pragma unroll
                for (int ni = 0; ni < 4; ++ni) {
                    if (SWAPPED)
                        acc[mi][ni] = __builtin_amdgcn_mfma_f32_16x16x32_bf16(
                            bf[ni], af[mi], acc[mi][ni], 0, 0, 0);
                    else
                        acc[mi][ni] = __builtin_amdgcn_mfma_f32_16x16x32_bf16(
                            af[mi], bf[ni], acc[mi][ni], 0, 0, 0);
                }
        }
        __syncthreads();
    }
}

// ---------------------------------------------------------------------------
// Kernel 1: QKV projection, bf16 MFMA.  Grid (12, 64) — round-9 verified.
// ---------------------------------------------------------------------------
__global__ __launch_bounds__(256) void qkv_gemm_mfma(
    const ushort_t* __restrict__ Xb, const ushort_t* __restrict__ Wt,
    const float* __restrict__ bq, const float* __restrict__ bk,
    const float* __restrict__ bv,
    ushort_t* __restrict__ Q, ushort_t* __restrict__ K, ushort_t* __restrict__ V)
{
    __shared__ __align__(16) ushort_t As[128 * 64];
    __shared__ __align__(16) ushort_t Bs[128 * 64];

    const int bx = blockIdx.x;          // 0..11
    const int m0 = blockIdx.y * 128;
    const int n0 = bx * 128;
    const int which = bx >> 2;          // 0=Q 1=K 2=V
    const bool isV = (which == 2);

    floatx4 acc[4][4];
#pragma unroll
    for (int i = 0; i < 4; ++i)
#pragma unroll
        for (int j = 0; j < 4; ++j) acc[i][j] = (floatx4)0.0f;

    if (isV) gemm128<TDIM, false>(Xb, Wt, m0, n0, As, Bs, acc);
    else     gemm128<TDIM, true >(Xb, Wt, m0, n0, As, Bs, acc);

    const int lane = threadIdx.x & 63;
    const int w    = threadIdx.x >> 6;
    const int l15  = lane & 15;
    const int quad = lane >> 4;
    const int wrow = w >> 1;
    const int wcol = w & 1;

    if (!isV) {
        const float* bias = (which == 0) ? bq : bk;
        const float scale = (which == 0) ? QSCALE : 1.0f;
        ushort_t* Out = (which == 0) ? Q : K;
#pragma unroll
        for (int mi = 0; mi < 4; ++mi) {
            const int m = m0 + wrow * 64 + mi * 16 + l15;
            const int b = m >> 11;
            const int s = m & 2047;
#pragma unroll
            for (int ni = 0; ni < 4; ++ni) {
                const int c = (n0 - which * HID) + wcol * 64 + ni * 16 + quad * 4;
                const int h = c >> 6;
                const int d0 = c & 63;
                const floatx4 b4 = *(const floatx4*)(bias + c);
                short4v pk;
#pragma unroll
                for (int r = 0; r < 4; ++r)
                    pk[r] = (short)bf16_rne((acc[mi][ni][r] + b4[r]) * scale);
                *(short4v*)&Out[((size_t)(b * NHEADS + h) * SEQ + s) * HDIM + d0] = pk;
            }
        }
    } else {
#pragma unroll
        for (int ni = 0; ni < 4; ++ni) {
            const int c = (n0 - 2 * HID) + wcol * 64 + ni * 16 + l15;
            const int h = c >> 6;
            const int d = c & 63;
            const float b1 = bv[c];
#pragma unroll
            for (int mi = 0; mi < 4; ++mi) {
                const int mb = m0 + wrow * 64 + mi * 16 + quad * 4;
                const int b = mb >> 11;
                const int s0 = mb & 2047;
                short4v pk;
#pragma unroll
                for (int r = 0; r < 4; ++r)
                    pk[r] = (short)bf16_rne(acc[mi][ni][r] + b1);
                *(short4v*)&V[((size_t)(b * NHEADS + h) * HDIM + d) * SEQ + s0] = pk;
            }
        }
    }
}

// ---------------------------------------------------------------------------
// Kernel 2: MFMA flash attention v10 (bf16 in/out), 32x32x16 MFMA, kv-split.
// Round-11: conflicts -> 0 (6-bit swizzle verified) but flash stayed 55 us:
// MfmaUtil 24 / VALU 28 / Occ 19% = latency-bound at 1 block/CU (grid 256),
// 2 waves/SIMD, serial QK->softmax->PV chain per tile.
// Fix: parallelize KV. No-max softmax partials are LINEAR (l, O are plain
// sums over kv) -> two wave-groups process disjoint kv halves and combine by
// addition at the end. 512 threads = 2 groups x 4 waves; Q-tile 128 (wave wl
// owns q rows wl*32..+31 in BOTH groups); group g does kv [g*1024,(g+1)*1024).
// Grid (16,32) = 512 blocks = 2 blocks/CU -> 16 waves/CU (4/SIMD), v3-level
// occupancy with v9's halved LDS traffic.
// Per-tile math + read swizzle are v11-VERBATIM (verified, 0 conflicts).
// Staging: row = wl*16 + s*8 + srow, same swz(row)=(row&7)^((row>>3)&7),
// linear async16 dests (multi-async16/wave is GEMM-verified).
// Epilogue: group 1 writes (of, l) to the dead K/V LDS (j-major layout,
// conflict-free), group 0 adds, normalizes, stores.
// ---------------------------------------------------------------------------
__global__ __launch_bounds__(512) void flash_attn_mfma(
    const ushort_t* __restrict__ Q, const ushort_t* __restrict__ K,
    const ushort_t* __restrict__ Vt, ushort_t* __restrict__ Att)
{
    // [group][buf][K=0/V=1][64x64 bf16] = 64 KB; reused as combine buffer
    __shared__ __align__(16) ushort_t KVs[2][2][2][64 * 64];

    const int tid  = threadIdx.x;
    const int lane = tid & 63;
    const int w    = tid >> 6;     // wave 0..7
    const int g    = w >> 2;       // kv-group 0/1
    const int wl   = w & 3;        // wave within group
    const int l31  = lane & 31;
    const int hi   = lane >> 5;    // 0/1
    const int r7   = l31 & 7;
    const int a3   = l31 >> 3;     // row bits [4:3]

    const int bh = blockIdx.y;
    const int b  = bh >> 3;
    const int h  = bh & 7;
    const int q0 = blockIdx.x * 128;

    const ushort_t* Qb = Q  + (size_t)bh * SEQ * HDIM;
    const ushort_t* Kb = K  + (size_t)bh * SEQ * HDIM;
    const ushort_t* Vb = Vt + (size_t)bh * HDIM * SEQ;

    // Q B-frags: col=q=l31, k = d = dstep*16+hi*8+j  (same q rows per group)
    short8 qf[4];
    {
        const ushort_t* qrow = Qb + (size_t)(q0 + wl * 32 + l31) * HDIM + hi * 8;
#pragma unroll
        for (int d = 0; d < 4; ++d) qf[d] = *(const short8*)(qrow + d * 16);
    }

    floatx16 of0 = (floatx16)0.0f;   // O^T rows d 0..31  (col q = l31)
    floatx16 of1 = (floatx16)0.0f;   // O^T rows d 32..63
    float l_run = 0.f;

    const floatx16 z16 = (floatx16)0.0f;

    // staging: wave wl stages tile rows wl*16 + s*8 + srow (s = 0,1).
    // swz(row) = (row&7) ^ ((row>>3)&7) = srow ^ (wl*2 + s)  — round-11 fn.
    const int srow  = lane >> 3;
    const int scol0 = (((lane & 7) ^ srow) ^ (wl * 2 + 0)) * 8;
    const int scol1 = (((lane & 7) ^ srow) ^ (wl * 2 + 1)) * 8;
    const int ktg   = g * 1024;                 // group kv base

    const ushort_t* gk0 = Kb + (size_t)(wl * 16 + srow) * HDIM + scol0;
    const ushort_t* gk1 = Kb + (size_t)(wl * 16 + 8 + srow) * HDIM + scol1;
    const ushort_t* gv0 = Vb + (size_t)(wl * 16 + srow) * SEQ + scol0;
    const ushort_t* gv1 = Vb + (size_t)(wl * 16 + 8 + srow) * SEQ + scol1;

    auto stage = [&](int buf, int kt) {
        async16(gk0 + (size_t)kt * HDIM, &KVs[g][buf][0][(wl * 16) * 64]);
        async16(gk1 + (size_t)kt * HDIM, &KVs[g][buf][0][(wl * 16 + 8) * 64]);
        async16(gv0 + kt,                &KVs[g][buf][1][(wl * 16) * 64]);
        async16(gv1 + kt,                &KVs[g][buf][1][(wl * 16 + 8) * 64]);
    };

    auto tile = [&](const ushort_t* Kt, const ushort_t* Vt_) {
        // ---- S^T = K . Q^T : 2 kv-subtiles x 4 d-steps ----
        floatx16 sacc0 = z16, sacc1 = z16;
        __builtin_amdgcn_s_setprio(1);
#pragma unroll
        for (int d = 0; d < 4; ++d) {
            const int sl = ((2 * d + hi) ^ r7 ^ a3) * 8;
            const short8 kf0 = *(const short8*)&Kt[l31 * 64 + sl];
            const short8 kf1 = *(const short8*)&Kt[(32 + l31) * 64 + (sl ^ 32)];
            sacc0 = __builtin_amdgcn_mfma_f32_32x32x16_bf16(kf0, qf[d], sacc0, 0, 0, 0);
            sacc1 = __builtin_amdgcn_mfma_f32_32x32x16_bf16(kf1, qf[d], sacc1, 0, 0, 0);
        }
        __builtin_amdgcn_s_setprio(0);

        // ---- p = exp2(s); pack quads to bf16x2; accumulate l on VALU ----
        unsigned ua[8], ub[8];
        float rs = 0.f;
#pragma unroll
        for (int gq = 0; gq < 4; ++gq) {
            const float p0 = __builtin_amdgcn_exp2f(sacc0[gq * 4 + 0]);
            const float p1 = __builtin_amdgcn_exp2f(sacc0[gq * 4 + 1]);
            const float p2 = __builtin_amdgcn_exp2f(sacc0[gq * 4 + 2]);
            const float p3 = __builtin_amdgcn_exp2f(sacc0[gq * 4 + 3]);
            rs += (p0 + p1) + (p2 + p3);
            asm("v_cvt_pk_bf16_f32 %0, %1, %2" : "=v"(ua[2 * gq])     : "v"(p0), "v"(p1));
            asm("v_cvt_pk_bf16_f32 %0, %1, %2" : "=v"(ua[2 * gq + 1]) : "v"(p2), "v"(p3));
        }
#pragma unroll
        for (int gq = 0; gq < 4; ++gq) {
            const float p0 = __builtin_amdgcn_exp2f(sacc1[gq * 4 + 0]);
            const float p1 = __builtin_amdgcn_exp2f(sacc1[gq * 4 + 1]);
            const float p2 = __builtin_amdgcn_exp2f(sacc1[gq * 4 + 2]);
            const float p3 = __builtin_amdgcn_exp2f(sacc1[gq * 4 + 3]);
            rs += (p0 + p1) + (p2 + p3);
            asm("v_cvt_pk_bf16_f32 %0, %1, %2" : "=v"(ub[2 * gq])     : "v"(p0), "v"(p1));
            asm("v_cvt_pk_bf16_f32 %0, %1, %2" : "=v"(ub[2 * gq + 1]) : "v"(p2), "v"(p3));
        }
        l_run += rs;

        // ---- build P^T B-frags: one permlane32_swap per packed pair ----
        short8 pfr[4];
#pragma unroll
        for (int t = 0; t < 2; ++t) {
            unsigned x0 = ua[4 * t + 0], y0 = ua[4 * t + 2];
            asm("v_permlane32_swap_b32 %0, %1" : "+v"(x0), "+v"(y0));
            unsigned x1 = ua[4 * t + 1], y1 = ua[4 * t + 3];
            asm("v_permlane32_swap_b32 %0, %1" : "+v"(x1), "+v"(y1));
            union { unsigned u[4]; short8 s8; } P;
            P.u[0] = x0; P.u[1] = x1; P.u[2] = y0; P.u[3] = y1;
            pfr[t] = P.s8;
        }
#pragma unroll
        for (int t = 0; t < 2; ++t) {
            unsigned x0 = ub[4 * t + 0], y0 = ub[4 * t + 2];
            asm("v_permlane32_swap_b32 %0, %1" : "+v"(x0), "+v"(y0));
            unsigned x1 = ub[4 * t + 1], y1 = ub[4 * t + 3];
            asm("v_permlane32_swap_b32 %0, %1" : "+v"(x1), "+v"(y1));
            union { unsigned u[4]; short8 s8; } P;
            P.u[0] = x0; P.u[1] = x1; P.u[2] = y0; P.u[3] = y1;
            pfr[2 + t] = P.s8;
        }

        // ---- O^T += V^T . P^T : 2 d-subtiles x 4 kv-steps ----
        __builtin_amdgcn_s_setprio(1);
#pragma unroll
        for (int ks = 0; ks < 4; ++ks) {
            const int sl = ((2 * ks + hi) ^ r7 ^ a3) * 8;
            const short8 vf0 = *(const short8*)&Vt_[l31 * 64 + sl];
            const short8 vf1 = *(const short8*)&Vt_[(32 + l31) * 64 + (sl ^ 32)];
            of0 = __builtin_amdgcn_mfma_f32_32x32x16_bf16(vf0, pfr[ks], of0, 0, 0, 0);
            of1 = __builtin_amdgcn_mfma_f32_32x32x16_bf16(vf1, pfr[ks], of1, 0, 0, 0);
        }
        __builtin_amdgcn_s_setprio(0);
    };

    // prologue: group's tile 0 into buf0
    stage(0, ktg);

    for (int kt = ktg; kt < ktg + 1024; kt += 128) {
        __syncthreads();                       // drains buf0 loads (vmcnt(0))
        stage(1, kt + 64);                     // prefetch buf1
        tile(KVs[g][0][0], KVs[g][0][1]);

        __syncthreads();                       // drains buf1 loads
        if (kt + 128 < ktg + 1024) stage(0, kt + 128);   // prefetch buf0
        tile(KVs[g][1][0], KVs[g][1][1]);
    }

    // ---- combine the two kv-groups (linear: no-max softmax partials) ----
    __syncthreads();                           // all tiles consumed; KVs dead
    float* Cf = (float*)KVs;                   // [32][4 waves][64 lanes] floats
    float* Lf = Cf + 32 * 256;                 // [4][64]
    if (g == 1) {
#pragma unroll
        for (int j = 0; j < 16; ++j) {
            Cf[j * 256 + wl * 64 + lane]        = of0[j];
            Cf[(16 + j) * 256 + wl * 64 + lane] = of1[j];
        }
        Lf[wl * 64 + lane] = l_run;
    }
    __syncthreads();
    if (g == 0) {
#pragma unroll
        for (int j = 0; j < 16; ++j) {
            of0[j] += Cf[j * 256 + wl * 64 + lane];
            of1[j] += Cf[(16 + j) * 256 + wl * 64 + lane];
        }
        l_run += Lf[wl * 64 + lane];
        l_run += __shfl_xor(l_run, 32);        // partner holds other kv half
        const float inv = 1.f / l_run;

        const int s = q0 + wl * 32 + l31;
        ushort_t* arow = Att + ((size_t)(b * SEQ + s)) * HID + h * HDIM;
#pragma unroll
        for (int rq = 0; rq < 4; ++rq) {
            short4v pk0, pk1;
#pragma unroll
            for (int j = 0; j < 4; ++j) {
                pk0[j] = (short)bf16_rne(of0[rq * 4 + j] * inv);
                pk1[j] = (short)bf16_rne(of1[rq * 4 + j] * inv);
            }
            *(short4v*)&arow[rq * 8 + hi * 4]      = pk0;   // d = rq*8+hi*4+j
            *(short4v*)&arow[32 + rq * 8 + hi * 4] = pk1;
        }
    }
}

// ---------------------------------------------------------------------------
// Kernel 3: output projection, bf16 MFMA.  Grid (6, 64) — round-9 verified.
// ---------------------------------------------------------------------------
__global__ __launch_bounds__(256) void out_gemm_mfma(
    const ushort_t* __restrict__ Attb, const ushort_t* __restrict__ Wot,
    const float* __restrict__ bo, float* __restrict__ Y)
{
    __shared__ __align__(16) ushort_t As[128 * 64];
    __shared__ __align__(16) ushort_t Bs[128 * 64];

    const int m0 = blockIdx.y * 128;
    const int n0 = blockIdx.x * 128;

    floatx4 acc[4][4];
#pragma unroll
    for (int i = 0; i < 4; ++i)
#pragma unroll
        for (int j = 0; j < 4; ++j) acc[i][j] = (floatx4)0.0f;

    gemm128<HID, true>(Attb, Wot, m0, n0, As, Bs, acc);

    const int lane = threadIdx.x & 63;
    const int w    = threadIdx.x >> 6;
    const int l15  = lane & 15;
    const int quad = lane >> 4;
    const int wrow = w >> 1;
    const int wcol = w & 1;

#pragma unroll
    for (int mi = 0; mi < 4; ++mi) {
        const int m = m0 + wrow * 64 + mi * 16 + l15;
#pragma unroll
        for (int ni = 0; ni < 4; ++ni) {
            const int nb = n0 + wcol * 64 + ni * 16 + quad * 4;
            const floatx4 b4 = *(const floatx4*)(bo + nb);
            floatx4 o;
#pragma unroll
            for (int r = 0; r < 4; ++r) o[r] = acc[mi][ni][r] + b4[r];
            *(floatx4*)&Y[(size_t)m * VDIM + nb] = o;
        }
    }
}

// ---------------------------------------------------------------------------
extern "C" void kernel_launch(void* const* d_in, const int* in_sizes, int n_in,
                              void* d_out, int out_size, void* d_ws, size_t ws_size,
                              hipStream_t stream)
{
    const float* text = (const float*)d_in[0];
    const float* Wq = (const float*)d_in[1];
    const float* bq = (const float*)d_in[2];
    const float* Wk = (const float*)d_in[3];
    const float* bk = (const float*)d_in[4];
    const float* Wv = (const float*)d_in[5];
    const float* bv = (const float*)d_in[6];
    const float* Wo = (const float*)d_in[7];
    const float* bo = (const float*)d_in[8];
    float* out = (float*)d_out;

    // ws layout (bf16): Xb | Wqkvt | Wot | Q | K | Vt | Attb  (~49 MB)
    ushort_t* Xb    = (ushort_t*)d_ws;
    ushort_t* Wqkvt = Xb + (size_t)MROWS * TDIM;
    ushort_t* Wot   = Wqkvt + (size_t)NQKV * TDIM;
    ushort_t* Qw    = Wot + (size_t)VDIM * HID;
    ushort_t* Kw    = Qw + (size_t)MROWS * HID;
    ushort_t* Vtw   = Kw + (size_t)MROWS * HID;
    ushort_t* Attb  = Vtw + (size_t)MROWS * HID;

    conv_x<<<dim3(MROWS * TDIM / 1024), 256, 0, stream>>>(text, Xb);
    transp_w<<<dim3(24, 24, 4), 256, 0, stream>>>(Wq, Wk, Wv, Wo, Wqkvt, Wot);
    qkv_gemm_mfma<<<dim3(12, 64), 256, 0, stream>>>(Xb, Wqkvt, bq, bk, bv, Qw, Kw, Vtw);
    flash_attn_mfma<<<dim3(16, 32), 512, 0, stream>>>(Qw, Kw, Vtw, Attb);
    out_gemm_mfma<<<dim3(6, 64), 256, 0, stream>>>(Attb, Wot, bo, out);
}

// Round 13
// 185.317 us; speedup vs baseline: 1.0360x; 1.0360x over previous
//
#include <hip/hip_runtime.h>
#include <hip/hip_bf16.h>

// B=4, S=2048, TEXT_DIM=768, VISION_DIM=768, HIDDEN=512, HEADS=8, HEAD_DIM=64
#define BATCH 4
#define SEQ 2048
#define TDIM 768
#define VDIM 768
#define HID 512
#define NHEADS 8
#define HDIM 64
#define MROWS (BATCH * SEQ)   // 8192
#define NQKV (3 * HID)        // 1536
#define NCONV (MROWS * TDIM / 1024)   // 6144 conv blocks

typedef unsigned short ushort_t;
typedef __attribute__((ext_vector_type(8))) short short8;
typedef __attribute__((ext_vector_type(4))) short short4v;
typedef __attribute__((ext_vector_type(4))) float floatx4;

// 0.125 * log2(e): folded into Q so softmax uses exp2
#define QSCALE 0.18033688011112042f

__device__ __forceinline__ ushort_t bf16_rne(float f) {
    unsigned int u = __float_as_uint(f);
    u = (u + 0x7fffu + ((u >> 16) & 1u)) >> 16;
    return (ushort_t)u;
}

__device__ __forceinline__ void async16(const ushort_t* g, ushort_t* l) {
    __builtin_amdgcn_global_load_lds(
        (const __attribute__((address_space(1))) unsigned int*)g,
        (__attribute__((address_space(3))) unsigned int*)l, 16, 0, 0);
}

// ---------------------------------------------------------------------------
// Merged pre-pass: conv (X fp32->bf16) + weight transposes, ONE dispatch.
// Round-13: tests the launch-overhead hypothesis at zero risk — per-block
// work is byte-identical to the two verified kernels; branch is block-uniform
// so the transp-side __syncthreads is safe.
// Grid: 6144 conv blocks + 4*24*24=2304 transp blocks = 8448.
// ---------------------------------------------------------------------------
__global__ __launch_bounds__(256) void prepass(
    const float* __restrict__ X,
    const float* __restrict__ Wq, const float* __restrict__ Wk,
    const float* __restrict__ Wv, const float* __restrict__ Wo,
    ushort_t* __restrict__ Xb,
    ushort_t* __restrict__ Wqkvt, ushort_t* __restrict__ Wot)
{
    __shared__ float tile[32][33];
    const int bx = blockIdx.x;

    if (bx < NCONV) {   // ---- conv region ----
        const int i = (bx * 256 + threadIdx.x) * 4;
        const floatx4 v = *(const floatx4*)(X + i);
        short4v o;
#pragma unroll
        for (int j = 0; j < 4; ++j) o[j] = (short)bf16_rne(v[j]);
        *(short4v*)(Xb + i) = o;
        return;
    }

    // ---- transp region ----
    const int t  = bx - NCONV;
    const int z  = t / 576;           // 0..3
    const int r  = t - z * 576;
    const int by = r / 24;
    const int bxx = r - by * 24;

    const float* src;
    ushort_t* dst;
    int R, C;
    if (z < 3) {
        src = (z == 0) ? Wq : (z == 1) ? Wk : Wv;
        dst = Wqkvt + (size_t)z * HID * TDIM;
        R = TDIM; C = HID;
    } else {
        src = Wo; dst = Wot; R = HID; C = VDIM;
    }
    const int tx = threadIdx.x & 31, ty = threadIdx.x >> 5;  // 32 x 8
    const int c0 = bxx * 32, r0 = by * 32;
    if (c0 >= C || r0 >= R) return;
#pragma unroll
    for (int i = 0; i < 4; ++i)
        tile[ty + i * 8][tx] = src[(size_t)(r0 + ty + i * 8) * C + c0 + tx];
    __syncthreads();
#pragma unroll
    for (int i = 0; i < 4; ++i)
        dst[(size_t)(c0 + ty + i * 8) * R + r0 + tx] = bf16_rne(tile[tx][ty + i * 8]);
}

// ---------------------------------------------------------------------------
// m97-style bf16 MFMA GEMM mainloop: C(128x128) = A[M][K] x Bt[N][K]^T.
// XOR-swizzled LDS (round-9, verified: bank conflicts -> 0, -11.5 us total).
// ---------------------------------------------------------------------------
template<int KD, bool SWAPPED>
__device__ __forceinline__ void gemm128(
    const ushort_t* __restrict__ A, const ushort_t* __restrict__ Bt,
    int m0, int n0, ushort_t* As, ushort_t* Bs, floatx4 (&acc)[4][4])
{
    const int tid  = threadIdx.x;
    const int lane = tid & 63;
    const int w    = tid >> 6;
    const int l15  = lane & 15;
    const int quad = lane >> 4;
    const int wrow = w >> 1;
    const int wcol = w & 1;

    const int srow = lane >> 3;                  // 0..7 = row&7
    const int scol = ((lane & 7) ^ srow) * 8;    // swizzled k elem offset

    const ushort_t* ga = A  + (size_t)(m0 + w * 32 + srow) * KD + scol;
    const ushort_t* gb = Bt + (size_t)(n0 + w * 32 + srow) * KD + scol;
    ushort_t* la = As + (w * 32) * 64;
    ushort_t* lb = Bs + (w * 32) * 64;

    for (int kt = 0; kt < KD; kt += 64) {
#pragma unroll
        for (int i = 0; i < 4; ++i) {
            async16(ga + (size_t)(i * 8) * KD + kt, la + i * 8 * 64);
            async16(gb + (size_t)(i * 8) * KD + kt, lb + i * 8 * 64);
        }
        __syncthreads();
#pragma unroll
        for (int half = 0; half < 2; ++half) {
            const int kk = ((half * 4 + quad) ^ (l15 & 7)) * 8;
            short8 af[4], bf[4];
#pragma unroll
            for (int t = 0; t < 4; ++t) {
                af[t] = *(const short8*)&As[(wrow * 64 + t * 16 + l15) * 64 + kk];
                bf[t] = *(const short8*)&Bs[(wcol * 64 + t * 16 + l15) * 64 + kk];
            }
#pragma unroll
            for (int mi = 0; mi < 4; ++mi)
#pragma unroll
                for (int ni = 0; ni < 4; ++ni) {
                    if (SWAPPED)
                        acc[mi][ni] = __builtin_amdgcn_mfma_f32_16x16x32_bf16(
                            bf[ni], af[mi], acc[mi][ni], 0, 0, 0);
                    else
                        acc[mi][ni] = __builtin_amdgcn_mfma_f32_16x16x32_bf16(
                            af[mi], bf[ni], acc[mi][ni], 0, 0, 0);
                }
        }
        __syncthreads();
    }
}

// ---------------------------------------------------------------------------
// Kernel 1: QKV projection, bf16 MFMA.  Grid (12, 64) — round-9 verified.
// ---------------------------------------------------------------------------
__global__ __launch_bounds__(256) void qkv_gemm_mfma(
    const ushort_t* __restrict__ Xb, const ushort_t* __restrict__ Wt,
    const float* __restrict__ bq, const float* __restrict__ bk,
    const float* __restrict__ bv,
    ushort_t* __restrict__ Q, ushort_t* __restrict__ K, ushort_t* __restrict__ V)
{
    __shared__ __align__(16) ushort_t As[128 * 64];
    __shared__ __align__(16) ushort_t Bs[128 * 64];

    const int bx = blockIdx.x;          // 0..11
    const int m0 = blockIdx.y * 128;
    const int n0 = bx * 128;
    const int which = bx >> 2;          // 0=Q 1=K 2=V
    const bool isV = (which == 2);

    floatx4 acc[4][4];
#pragma unroll
    for (int i = 0; i < 4; ++i)
#pragma unroll
        for (int j = 0; j < 4; ++j) acc[i][j] = (floatx4)0.0f;

    if (isV) gemm128<TDIM, false>(Xb, Wt, m0, n0, As, Bs, acc);
    else     gemm128<TDIM, true >(Xb, Wt, m0, n0, As, Bs, acc);

    const int lane = threadIdx.x & 63;
    const int w    = threadIdx.x >> 6;
    const int l15  = lane & 15;
    const int quad = lane >> 4;
    const int wrow = w >> 1;
    const int wcol = w & 1;

    if (!isV) {
        const float* bias = (which == 0) ? bq : bk;
        const float scale = (which == 0) ? QSCALE : 1.0f;
        ushort_t* Out = (which == 0) ? Q : K;
#pragma unroll
        for (int mi = 0; mi < 4; ++mi) {
            const int m = m0 + wrow * 64 + mi * 16 + l15;
            const int b = m >> 11;
            const int s = m & 2047;
#pragma unroll
            for (int ni = 0; ni < 4; ++ni) {
                const int c = (n0 - which * HID) + wcol * 64 + ni * 16 + quad * 4;
                const int h = c >> 6;
                const int d0 = c & 63;
                const floatx4 b4 = *(const floatx4*)(bias + c);
                short4v pk;
#pragma unroll
                for (int r = 0; r < 4; ++r)
                    pk[r] = (short)bf16_rne((acc[mi][ni][r] + b4[r]) * scale);
                *(short4v*)&Out[((size_t)(b * NHEADS + h) * SEQ + s) * HDIM + d0] = pk;
            }
        }
    } else {
#pragma unroll
        for (int ni = 0; ni < 4; ++ni) {
            const int c = (n0 - 2 * HID) + wcol * 64 + ni * 16 + l15;
            const int h = c >> 6;
            const int d = c & 63;
            const float b1 = bv[c];
#pragma unroll
            for (int mi = 0; mi < 4; ++mi) {
                const int mb = m0 + wrow * 64 + mi * 16 + quad * 4;
                const int b = mb >> 11;
                const int s0 = mb & 2047;
                short4v pk;
#pragma unroll
                for (int r = 0; r < 4; ++r)
                    pk[r] = (short)bf16_rne(acc[mi][ni][r] + b1);
                *(short4v*)&V[((size_t)(b * NHEADS + h) * HDIM + d) * SEQ + s0] = pk;
            }
        }
    }
}

// ---------------------------------------------------------------------------
// Kernel 2: MFMA flash attention — v3 VERBATIM (round-1/9: 47.7-48 us,
// passed, absmax 4.88e-4; within 17% of its 41-us LDS-pipe floor).
// Closed lines: dual-qi 16x16 (2x miscompute ~7.2e-3); direct-global K
// (latency-bound, 134 us); 32x32 family incl. kv-split (50.4 best — barrier
// lockstep bursts the pipes in phase, never beat 48).
// ---------------------------------------------------------------------------
__global__ __launch_bounds__(512) void flash_attn_mfma(
    const ushort_t* __restrict__ Q, const ushort_t* __restrict__ K,
    const ushort_t* __restrict__ Vt, ushort_t* __restrict__ Att)
{
    __shared__ __align__(16) ushort_t Ks[2][64 * 64];   // [buf][kk][d]  (swizzled)
    __shared__ __align__(16) ushort_t Vs[2][64 * 64];   // [buf][d][kk]  (swizzled)

    const int tid  = threadIdx.x;
    const int lane = tid & 63;
    const int w    = tid >> 6;     // wave 0..7
    const int l15  = lane & 15;
    const int quad = lane >> 4;

    const int bh = blockIdx.y;
    const int b  = bh >> 3;
    const int h  = bh & 7;
    const int q0 = blockIdx.x * 128;

    const ushort_t* Qb = Q  + (size_t)bh * SEQ * HDIM;
    const ushort_t* Kb = K  + (size_t)bh * SEQ * HDIM;
    const ushort_t* Vb = Vt + (size_t)bh * HDIM * SEQ;

    // Q fragments (registers, whole kernel). B-operand: n=q=l15, k=d=quad*8+j
    short8 qf0, qf1;
    {
        const ushort_t* qrow = Qb + (size_t)(q0 + w * 16 + l15) * HDIM + quad * 8;
        qf0 = *(const short8*)(qrow);
        qf1 = *(const short8*)(qrow + 32);
    }

    floatx4 of[4];
#pragma unroll
    for (int t = 0; t < 4; ++t) of[t] = (floatx4)0.0f;
    floatx4 ofl = (floatx4)0.0f;          // l accumulator via ones-MFMA

    short8 ones;
#pragma unroll
    for (int j = 0; j < 8; ++j) ones[j] = (short)0x3F80;   // bf16 1.0

    const floatx4 z4 = (floatx4)0.0f;

    // staging: wave w stages rows w*8..w*8+7 of each tile.
    // global source col16 is pre-swizzled so the LINEAR global_load_lds dest
    // (base + lane*16) lands the XOR-swizzled layout.
    const int srow = lane >> 3;                    // 0..7 = row&7
    const int scol = ((lane & 7) ^ srow) * 8;      // swizzled col (elems)
    const ushort_t* gk = Kb + (size_t)(w * 8 + srow) * HDIM + scol;
    const ushort_t* gv = Vb + (size_t)(w * 8 + srow) * SEQ + scol;
    ushort_t* lk0 = &Ks[0][w * 8 * 64];            // wave-uniform LDS bases
    ushort_t* lk1 = &Ks[1][w * 8 * 64];
    ushort_t* lv0 = &Vs[0][w * 8 * 64];
    ushort_t* lv1 = &Vs[1][w * 8 * 64];

    // fragment read offsets (swizzle-aware): global col16 c of row r sits at
    // LDS slot c ^ (r&7); r&7 == l15&7 for all t (t*16 = 0 mod 8).
    const int off0 = (quad ^ (l15 & 7)) * 8;       // elems, kv/d half 0
    const int off1 = off0 ^ 32;                    // (slot^4)*8, half 1

    auto tile = [&](const ushort_t* Kt, const ushort_t* Vt_) {
        // ---- S^T = K . Q^T ----
        floatx4 sacc[4];
        __builtin_amdgcn_s_setprio(1);
#pragma unroll
        for (int t = 0; t < 4; ++t) {
            const short8 kf0 = *(const short8*)&Kt[(t * 16 + l15) * 64 + off0];
            const short8 kf1 = *(const short8*)&Kt[(t * 16 + l15) * 64 + off1];
            floatx4 a = z4;
            a = __builtin_amdgcn_mfma_f32_16x16x32_bf16(kf0, qf0, a, 0, 0, 0);
            a = __builtin_amdgcn_mfma_f32_16x16x32_bf16(kf1, qf1, a, 0, 0, 0);
            sacc[t] = a;
        }
        __builtin_amdgcn_s_setprio(0);

        // ---- p = exp2(s) (raw v_exp_f32), pack pairs to bf16x2 ----
        // lane holds p for q=l15, kv = 16t + 4*quad + r
        unsigned w0[4], w1[4];
#pragma unroll
        for (int t = 0; t < 4; ++t) {
            const float p0 = __builtin_amdgcn_exp2f(sacc[t][0]);
            const float p1 = __builtin_amdgcn_exp2f(sacc[t][1]);
            const float p2 = __builtin_amdgcn_exp2f(sacc[t][2]);
            const float p3 = __builtin_amdgcn_exp2f(sacc[t][3]);
            asm("v_cvt_pk_bf16_f32 %0, %1, %2" : "=v"(w0[t]) : "v"(p0), "v"(p1));
            asm("v_cvt_pk_bf16_f32 %0, %1, %2" : "=v"(w1[t]) : "v"(p2), "v"(p3));
        }

        // ---- in-register P^T redistribution (dest b5'=t, b4'=src b5) ----
        unsigned a0 = w0[0], b0 = w0[1];
        asm("v_permlane32_swap_b32 %0, %1" : "+v"(a0), "+v"(b0));
        asm("v_permlane16_swap_b32 %0, %1" : "+v"(a0), "+v"(b0));
        unsigned a1 = w1[0], b1 = w1[1];
        asm("v_permlane32_swap_b32 %0, %1" : "+v"(a1), "+v"(b1));
        asm("v_permlane16_swap_b32 %0, %1" : "+v"(a1), "+v"(b1));
        unsigned a2 = w0[2], b2 = w0[3];
        asm("v_permlane32_swap_b32 %0, %1" : "+v"(a2), "+v"(b2));
        asm("v_permlane16_swap_b32 %0, %1" : "+v"(a2), "+v"(b2));
        unsigned a3 = w1[2], b3 = w1[3];
        asm("v_permlane32_swap_b32 %0, %1" : "+v"(a3), "+v"(b3));
        asm("v_permlane16_swap_b32 %0, %1" : "+v"(a3), "+v"(b3));

        union { unsigned u[4]; short8 s; } P0, P1;
        P0.u[0] = a0; P0.u[1] = a1; P0.u[2] = b0; P0.u[3] = b1;   // kv 0..31
        P1.u[0] = a2; P1.u[1] = a3; P1.u[2] = b2; P1.u[3] = b3;   // kv 32..63
        const short8 pf0 = P0.s;
        const short8 pf1 = P1.s;

        // ---- O^T += V^T . P^T ; l += 1 . P^T (MFMA pipe) ----
        __builtin_amdgcn_s_setprio(1);
        ofl = __builtin_amdgcn_mfma_f32_16x16x32_bf16(ones, pf0, ofl, 0, 0, 0);
        ofl = __builtin_amdgcn_mfma_f32_16x16x32_bf16(ones, pf1, ofl, 0, 0, 0);
#pragma unroll
        for (int t = 0; t < 4; ++t) {
            const short8 vf0 = *(const short8*)&Vt_[(t * 16 + l15) * 64 + off0];
            const short8 vf1 = *(const short8*)&Vt_[(t * 16 + l15) * 64 + off1];
            of[t] = __builtin_amdgcn_mfma_f32_16x16x32_bf16(vf0, pf0, of[t], 0, 0, 0);
            of[t] = __builtin_amdgcn_mfma_f32_16x16x32_bf16(vf1, pf1, of[t], 0, 0, 0);
        }
        __builtin_amdgcn_s_setprio(0);
    };

    // prologue: tile 0 into buf0
    async16(gk, lk0);
    async16(gv, lv0);

    for (int kt = 0; kt < SEQ; kt += 128) {
        __syncthreads();                       // drains buf0 loads (vmcnt(0))
        async16(gk + (size_t)(kt + 64) * HDIM, lk1);   // prefetch buf1
        async16(gv + (kt + 64), lv1);
        tile(Ks[0], Vs[0]);

        __syncthreads();                       // drains buf1 loads
        if (kt + 128 < SEQ) {
            async16(gk + (size_t)(kt + 128) * HDIM, lk0);  // prefetch buf0
            async16(gv + (kt + 128), lv0);
        }
        tile(Ks[1], Vs[1]);
    }

    // ---- epilogue: each lane already holds full l for its q=l15 ----
    const float inv = 1.f / ofl[0];

    const int s = q0 + w * 16 + l15;
    ushort_t* arow = Att + ((size_t)(b * SEQ + s)) * HID + h * HDIM;
#pragma unroll
    for (int t = 0; t < 4; ++t) {
        short4v pk;
#pragma unroll
        for (int r = 0; r < 4; ++r) pk[r] = (short)bf16_rne(of[t][r] * inv);
        *(short4v*)&arow[t * 16 + quad * 4] = pk;
    }
}

// ---------------------------------------------------------------------------
// Kernel 3: output projection, bf16 MFMA.  Grid (6, 64) — round-9 verified.
// ---------------------------------------------------------------------------
__global__ __launch_bounds__(256) void out_gemm_mfma(
    const ushort_t* __restrict__ Attb, const ushort_t* __restrict__ Wot,
    const float* __restrict__ bo, float* __restrict__ Y)
{
    __shared__ __align__(16) ushort_t As[128 * 64];
    __shared__ __align__(16) ushort_t Bs[128 * 64];

    const int m0 = blockIdx.y * 128;
    const int n0 = blockIdx.x * 128;

    floatx4 acc[4][4];
#pragma unroll
    for (int i = 0; i < 4; ++i)
#pragma unroll
        for (int j = 0; j < 4; ++j) acc[i][j] = (floatx4)0.0f;

    gemm128<HID, true>(Attb, Wot, m0, n0, As, Bs, acc);

    const int lane = threadIdx.x & 63;
    const int w    = threadIdx.x >> 6;
    const int l15  = lane & 15;
    const int quad = lane >> 4;
    const int wrow = w >> 1;
    const int wcol = w & 1;

#pragma unroll
    for (int mi = 0; mi < 4; ++mi) {
        const int m = m0 + wrow * 64 + mi * 16 + l15;
#pragma unroll
        for (int ni = 0; ni < 4; ++ni) {
            const int nb = n0 + wcol * 64 + ni * 16 + quad * 4;
            const floatx4 b4 = *(const floatx4*)(bo + nb);
            floatx4 o;
#pragma unroll
            for (int r = 0; r < 4; ++r) o[r] = acc[mi][ni][r] + b4[r];
            *(floatx4*)&Y[(size_t)m * VDIM + nb] = o;
        }
    }
}

// ---------------------------------------------------------------------------
extern "C" void kernel_launch(void* const* d_in, const int* in_sizes, int n_in,
                              void* d_out, int out_size, void* d_ws, size_t ws_size,
                              hipStream_t stream)
{
    const float* text = (const float*)d_in[0];
    const float* Wq = (const float*)d_in[1];
    const float* bq = (const float*)d_in[2];
    const float* Wk = (const float*)d_in[3];
    const float* bk = (const float*)d_in[4];
    const float* Wv = (const float*)d_in[5];
    const float* bv = (const float*)d_in[6];
    const float* Wo = (const float*)d_in[7];
    const float* bo = (const float*)d_in[8];
    float* out = (float*)d_out;

    // ws layout (bf16): Xb | Wqkvt | Wot | Q | K | Vt | Attb  (~49 MB)
    ushort_t* Xb    = (ushort_t*)d_ws;
    ushort_t* Wqkvt = Xb + (size_t)MROWS * TDIM;
    ushort_t* Wot   = Wqkvt + (size_t)NQKV * TDIM;
    ushort_t* Qw    = Wot + (size_t)VDIM * HID;
    ushort_t* Kw    = Qw + (size_t)MROWS * HID;
    ushort_t* Vtw   = Kw + (size_t)MROWS * HID;
    ushort_t* Attb  = Vtw + (size_t)MROWS * HID;

    prepass<<<dim3(NCONV + 4 * 576), 256, 0, stream>>>(
        text, Wq, Wk, Wv, Wo, Xb, Wqkvt, Wot);
    qkv_gemm_mfma<<<dim3(12, 64), 256, 0, stream>>>(Xb, Wqkvt, bq, bk, bv, Qw, Kw, Vtw);
    flash_attn_mfma<<<dim3(16, 32), 512, 0, stream>>>(Qw, Kw, Vtw, Attb);
    out_gemm_mfma<<<dim3(6, 64), 256, 0, stream>>>(Attb, Wot, bo, out);
}